// Round 4
// baseline (253.498 us; speedup 1.0000x reference)
//
#include <hip/hip_runtime.h>
#include <math.h>

typedef __attribute__((ext_vector_type(8))) short bf16x8;
typedef __attribute__((ext_vector_type(8))) unsigned short u16x8;
typedef __attribute__((ext_vector_type(4))) unsigned short u16x4;
typedef __attribute__((ext_vector_type(4))) float f32x4;
typedef unsigned short u16;

__device__ __forceinline__ u16 f2bf(float f) {
  unsigned u = __builtin_bit_cast(unsigned, f);
  return (u16)((u + 0x7FFFu + ((u >> 16) & 1u)) >> 16);
}

__device__ __forceinline__ void gload16(const u16* g, u16* l) {
  __builtin_amdgcn_global_load_lds((const __attribute__((address_space(1))) void*)g,
                                   (__attribute__((address_space(3))) void*)l, 16, 0, 0);
}

__device__ __forceinline__ void sbar() {
  __builtin_amdgcn_sched_barrier(0);
  __builtin_amdgcn_s_barrier();
  __builtin_amdgcn_sched_barrier(0);
}

#define MFMA16(a, b, c) __builtin_amdgcn_mfma_f32_16x16x32_bf16((a), (b), (c), 0, 0, 0)

__device__ __forceinline__ float decay_of(float d) {
  return 1e-12f + 0.5f + 0.5f / (1.0f + expf(-d));
}

// ---------------- prep: f32 -> bf16 ----------------
__global__ __launch_bounds__(256) void cvt_bf16_kernel(const float* __restrict__ in,
                                                       u16* __restrict__ out, int n4) {
  int i = blockIdx.x * 256 + threadIdx.x;
  if (i >= n4) return;
  const float4 v = ((const float4*)in)[i];
  u16x4 o = { f2bf(v.x), f2bf(v.y), f2bf(v.z), f2bf(v.w) };
  ((u16x4*)out)[i] = o;
}

// ---------------- prep: relu(cp) transposed to [t][c] bf16 ----------------
__global__ __launch_bounds__(256) void relu_t_kernel(const float* __restrict__ cp,
                                                     u16* __restrict__ x0t) {
  const int cb = blockIdx.x & 31;
  const int tb = blockIdx.x >> 5;
  __shared__ __attribute__((aligned(16))) float tile[64][65];
  const int tid = threadIdx.x;
  const int r0 = tid >> 4, i4 = (tid & 15) * 4;
  #pragma unroll
  for (int rr = 0; rr < 64; rr += 16) {
    const float4 v = *(const float4*)(cp + (size_t)(cb * 64 + r0 + rr) * 4096 + tb * 64 + i4);
    tile[r0 + rr][i4 + 0] = fmaxf(v.x, 0.f);
    tile[r0 + rr][i4 + 1] = fmaxf(v.y, 0.f);
    tile[r0 + rr][i4 + 2] = fmaxf(v.z, 0.f);
    tile[r0 + rr][i4 + 3] = fmaxf(v.w, 0.f);
  }
  __syncthreads();
  #pragma unroll
  for (int it = 0; it < 2; ++it) {
    const int chunk = it * 256 + tid;
    const int i = chunk >> 3, rp = (chunk & 7) * 8;
    u16x8 o;
    #pragma unroll
    for (int q = 0; q < 8; ++q) o[q] = f2bf(tile[rp + q][i]);
    *(u16x8*)(x0t + (size_t)(tb * 64 + i) * 2048 + cb * 64 + rp) = o;
  }
}

// ---------------- IIR blocked scan ----------------
__global__ __launch_bounds__(128) void iir_partial_kernel(const float* __restrict__ x,
                                                          const float* __restrict__ decays,
                                                          float* __restrict__ L) {
  const int tid = threadIdx.x;
  const int cb = blockIdx.x & 15;
  const int ck = blockIdx.x >> 4;
  const int c0 = cb * 128, t0 = ck * 64;
  __shared__ __attribute__((aligned(16))) float xs[128][65];
  const float dd = decay_of(decays[c0 + tid]);
  #pragma unroll
  for (int it = 0; it < 16; ++it) {
    const int idx = it * 128 + tid;
    const int r = idx >> 4, iv = (idx & 15) * 4;
    const float4 v = *(const float4*)(x + (size_t)(c0 + r) * 4096 + t0 + iv);
    xs[r][iv + 0] = v.x; xs[r][iv + 1] = v.y; xs[r][iv + 2] = v.z; xs[r][iv + 3] = v.w;
  }
  __syncthreads();
  float yv = 0.0f;
  #pragma unroll
  for (int i = 0; i < 64; ++i) yv = dd * (xs[tid][i] + yv);
  L[ck * 2048 + c0 + tid] = yv;
}

__global__ __launch_bounds__(128) void iir_carry_kernel(const float* __restrict__ L,
                                                        const float* __restrict__ decays,
                                                        float* __restrict__ Cin) {
  const int c = blockIdx.x * 128 + threadIdx.x;
  const float dd = decay_of(decays[c]);
  float A = dd;
  #pragma unroll
  for (int p = 0; p < 6; ++p) A = A * A;   // dd^64
  float carry = 0.0f;
  for (int j = 0; j < 64; ++j) {
    Cin[j * 2048 + c] = carry;
    carry = L[j * 2048 + c] + A * carry;
  }
}

__global__ __launch_bounds__(128) void iir_apply_kernel(const float* __restrict__ x,
                                                        const float* __restrict__ decays,
                                                        const float* __restrict__ Cin,
                                                        u16* __restrict__ yT) {
  const int tid = threadIdx.x;
  const int cb = blockIdx.x & 15;
  const int ck = blockIdx.x >> 4;
  const int c0 = cb * 128, t0 = ck * 64;
  __shared__ __attribute__((aligned(16))) float xs[128][65];
  __shared__ __attribute__((aligned(16))) u16 ys[64][136];
  const float dd = decay_of(decays[c0 + tid]);
  const float carry = Cin[ck * 2048 + c0 + tid];
  #pragma unroll
  for (int it = 0; it < 16; ++it) {
    const int idx = it * 128 + tid;
    const int r = idx >> 4, iv = (idx & 15) * 4;
    const float4 v = *(const float4*)(x + (size_t)(c0 + r) * 4096 + t0 + iv);
    xs[r][iv + 0] = v.x; xs[r][iv + 1] = v.y; xs[r][iv + 2] = v.z; xs[r][iv + 3] = v.w;
  }
  __syncthreads();
  float yv = carry;
  #pragma unroll
  for (int i = 0; i < 64; ++i) {
    yv = dd * (xs[tid][i] + yv);
    ys[i][tid] = f2bf(yv);
  }
  __syncthreads();
  #pragma unroll
  for (int it = 0; it < 8; ++it) {
    const int chunk = it * 128 + tid;
    const int i = chunk >> 4, cpv = (chunk & 15) * 8;
    u16x8 v = *(const u16x8*)&ys[i][cpv];
    *(u16x8*)(yT + (size_t)(t0 + i) * 2048 + c0 + cpv) = v;
  }
}

// ---------------- GEMM: 256x128 tile, BK=64, triple-buffer, 2 pipelined phases ----------------
// C[M][N] = A[M][K] @ Bt[N][K]^T. 512 thr = 8 waves (4M x 2N), per-wave 64x64.
// m201-style: ds_reads issued BEFORE the phase barrier (latency hides in barrier
// convergence); vmcnt(6) gate at end of each iteration, barrier-ordered before
// the next iteration's reads. B-frags held in regs across phase 0 -> phase 1.
template <int MODE>
__global__ __launch_bounds__(512, 2) void gemm8_kernel(
    const u16* __restrict__ A, const u16* __restrict__ Bt, float* __restrict__ C,
    int N, int K, int xlog,
    const float* __restrict__ orig, const float* __restrict__ gains,
    u16* __restrict__ CbT) {
  __shared__ __attribute__((aligned(16))) u16 Asb[3][256 * 64];  // 96 KB
  __shared__ __attribute__((aligned(16))) u16 Bsb[3][128 * 64];  // 48 KB
  const int tid = threadIdx.x;
  const int l = tid & 63, w = tid >> 6;
  // XCD-rect swizzle: each XCD owns a 4bm x 8bn rectangle of the 256-block grid.
  const int xc = blockIdx.x & 7, rblk = blockIdx.x >> 3;
  const int bm = (xc >> xlog) * 4 + (rblk >> 3);
  const int bn = (xc & ((1 << xlog) - 1)) * 8 + (rblk & 7);
  const int nt = K >> 6;

  // staging: lane l covers row (unit*8+w)*8 + (l>>3), swizzled 16B chunk.
  // LDS[row][chunk] = G[row][chunk ^ (row&7)]  (involution; read side applies same XOR)
  const int cs = (l & 7) ^ (l >> 3);
  const int rsub = l >> 3;
  const u16* aS0 = A + (size_t)(bm * 256 + (0 * 8 + w) * 8 + rsub) * K + cs * 8;
  const u16* aS1 = A + (size_t)(bm * 256 + (1 * 8 + w) * 8 + rsub) * K + cs * 8;
  const u16* aS2 = A + (size_t)(bm * 256 + (2 * 8 + w) * 8 + rsub) * K + cs * 8;
  const u16* aS3 = A + (size_t)(bm * 256 + (3 * 8 + w) * 8 + rsub) * K + cs * 8;
  const u16* bS0 = Bt + (size_t)(bn * 128 + (0 * 8 + w) * 8 + rsub) * K + cs * 8;
  const u16* bS1 = Bt + (size_t)(bn * 128 + (1 * 8 + w) * 8 + rsub) * K + cs * 8;
  const int aO0 = (0 * 8 + w) * 512, aO1 = (1 * 8 + w) * 512;
  const int aO2 = (2 * 8 + w) * 512, aO3 = (3 * 8 + w) * 512;
  const int bO0 = (0 * 8 + w) * 512, bO1 = (1 * 8 + w) * 512;

  // prologue: stage tiles 0 and 1 (6 loads each)
  gload16(aS0, Asb[0] + aO0); gload16(aS1, Asb[0] + aO1);
  gload16(aS2, Asb[0] + aO2); gload16(aS3, Asb[0] + aO3);
  gload16(bS0, Bsb[0] + bO0); gload16(bS1, Bsb[0] + bO1);
  gload16(aS0 + 64, Asb[1] + aO0); gload16(aS1 + 64, Asb[1] + aO1);
  gload16(aS2 + 64, Asb[1] + aO2); gload16(aS3 + 64, Asb[1] + aO3);
  gload16(bS0 + 64, Bsb[1] + bO0); gload16(bS1 + 64, Bsb[1] + bO1);

  f32x4 acc[4][4];
  #pragma unroll
  for (int i = 0; i < 4; ++i)
    #pragma unroll
    for (int j = 0; j < 4; ++j) acc[i][j] = (f32x4){0.f, 0.f, 0.f, 0.f};

  const int wrM = w >> 1, wrN = w & 1;
  const int rA0 = wrM * 64 + (l & 15);
  const int rB0 = wrN * 64 + (l & 15);
  const int jk0 = ((l >> 4) + 0) ^ (l & 7);   // swizzled chunk, k-half 0
  const int jk1 = ((l >> 4) + 4) ^ (l & 7);   // swizzled chunk, k-half 1

  // gate tile 0 landed, barrier-ordered before first reads
  asm volatile("s_waitcnt vmcnt(6)" ::: "memory");
  sbar();

  for (int t = 0; t < nt; ++t) {
    const int cur = t % 3;
    const u16* Ac = Asb[cur];
    const u16* Bc = Bsb[cur];
    u16* Anx = Asb[(t + 2) % 3];
    u16* Bnx = Bsb[(t + 2) % 3];
    const bool st = (t + 2) < nt;
    const long so = (long)(t + 2) * 64;

    // ---- phase 0: stage half; read A(m0,m1) + all B; MFMA rows 0-1 ----
    if (st) { gload16(aS0 + so, Anx + aO0); gload16(aS1 + so, Anx + aO1);
              gload16(bS0 + so, Bnx + bO0); }
    bf16x8 a00 = *(const bf16x8*)(Ac + (rA0 + 0)  * 64 + jk0 * 8);
    bf16x8 a01 = *(const bf16x8*)(Ac + (rA0 + 0)  * 64 + jk1 * 8);
    bf16x8 a10 = *(const bf16x8*)(Ac + (rA0 + 16) * 64 + jk0 * 8);
    bf16x8 a11 = *(const bf16x8*)(Ac + (rA0 + 16) * 64 + jk1 * 8);
    bf16x8 bA0 = *(const bf16x8*)(Bc + (rB0 + 0)  * 64 + jk0 * 8);
    bf16x8 bA1 = *(const bf16x8*)(Bc + (rB0 + 0)  * 64 + jk1 * 8);
    bf16x8 bB0 = *(const bf16x8*)(Bc + (rB0 + 16) * 64 + jk0 * 8);
    bf16x8 bB1 = *(const bf16x8*)(Bc + (rB0 + 16) * 64 + jk1 * 8);
    bf16x8 bC0 = *(const bf16x8*)(Bc + (rB0 + 32) * 64 + jk0 * 8);
    bf16x8 bC1 = *(const bf16x8*)(Bc + (rB0 + 32) * 64 + jk1 * 8);
    bf16x8 bD0 = *(const bf16x8*)(Bc + (rB0 + 48) * 64 + jk0 * 8);
    bf16x8 bD1 = *(const bf16x8*)(Bc + (rB0 + 48) * 64 + jk1 * 8);
    sbar();
    __builtin_amdgcn_s_setprio(1);
    acc[0][0] = MFMA16(a00, bA0, acc[0][0]); acc[0][1] = MFMA16(a00, bB0, acc[0][1]);
    acc[0][2] = MFMA16(a00, bC0, acc[0][2]); acc[0][3] = MFMA16(a00, bD0, acc[0][3]);
    acc[1][0] = MFMA16(a10, bA0, acc[1][0]); acc[1][1] = MFMA16(a10, bB0, acc[1][1]);
    acc[1][2] = MFMA16(a10, bC0, acc[1][2]); acc[1][3] = MFMA16(a10, bD0, acc[1][3]);
    acc[0][0] = MFMA16(a01, bA1, acc[0][0]); acc[0][1] = MFMA16(a01, bB1, acc[0][1]);
    acc[0][2] = MFMA16(a01, bC1, acc[0][2]); acc[0][3] = MFMA16(a01, bD1, acc[0][3]);
    acc[1][0] = MFMA16(a11, bA1, acc[1][0]); acc[1][1] = MFMA16(a11, bB1, acc[1][1]);
    acc[1][2] = MFMA16(a11, bC1, acc[1][2]); acc[1][3] = MFMA16(a11, bD1, acc[1][3]);
    __builtin_amdgcn_s_setprio(0);
    sbar();

    // ---- phase 1: stage rest; read A(m2,m3); B reused from regs; MFMA rows 2-3 ----
    if (st) { gload16(aS2 + so, Anx + aO2); gload16(aS3 + so, Anx + aO3);
              gload16(bS1 + so, Bnx + bO1); }
    a00 = *(const bf16x8*)(Ac + (rA0 + 32) * 64 + jk0 * 8);
    a01 = *(const bf16x8*)(Ac + (rA0 + 32) * 64 + jk1 * 8);
    a10 = *(const bf16x8*)(Ac + (rA0 + 48) * 64 + jk0 * 8);
    a11 = *(const bf16x8*)(Ac + (rA0 + 48) * 64 + jk1 * 8);
    sbar();
    __builtin_amdgcn_s_setprio(1);
    acc[2][0] = MFMA16(a00, bA0, acc[2][0]); acc[2][1] = MFMA16(a00, bB0, acc[2][1]);
    acc[2][2] = MFMA16(a00, bC0, acc[2][2]); acc[2][3] = MFMA16(a00, bD0, acc[2][3]);
    acc[3][0] = MFMA16(a10, bA0, acc[3][0]); acc[3][1] = MFMA16(a10, bB0, acc[3][1]);
    acc[3][2] = MFMA16(a10, bC0, acc[3][2]); acc[3][3] = MFMA16(a10, bD0, acc[3][3]);
    acc[2][0] = MFMA16(a01, bA1, acc[2][0]); acc[2][1] = MFMA16(a01, bB1, acc[2][1]);
    acc[2][2] = MFMA16(a01, bC1, acc[2][2]); acc[2][3] = MFMA16(a01, bD1, acc[2][3]);
    acc[3][0] = MFMA16(a11, bA1, acc[3][0]); acc[3][1] = MFMA16(a11, bB1, acc[3][1]);
    acc[3][2] = MFMA16(a11, bC1, acc[3][2]); acc[3][3] = MFMA16(a11, bD1, acc[3][3]);
    __builtin_amdgcn_s_setprio(0);
    // gate: tile t+1 fully landed before next iteration's reads (after barrier)
    if (st) { asm volatile("s_waitcnt vmcnt(6)" ::: "memory"); }
    else    { asm volatile("s_waitcnt vmcnt(0)" ::: "memory"); }
    sbar();
  }

  // ---------------- epilogue ----------------
  const int rb = bm * 256 + wrM * 64 + ((l >> 4) * 4);
  const int cb = bn * 128 + wrN * 64 + (l & 15);
  #pragma unroll
  for (int mi = 0; mi < 4; ++mi) {
    const int row0 = rb + mi * 16;
    float gv0 = 0.f, gv1 = 0.f, gv2 = 0.f, gv3 = 0.f;
    if (MODE == 1) {
      gv0 = 5.0f / (1.0f + expf(-gains[row0 + 0]));
      gv1 = 5.0f / (1.0f + expf(-gains[row0 + 1]));
      gv2 = 5.0f / (1.0f + expf(-gains[row0 + 2]));
      gv3 = 5.0f / (1.0f + expf(-gains[row0 + 3]));
    }
    #pragma unroll
    for (int ni = 0; ni < 4; ++ni) {
      const int col = cb + ni * 16;
      f32x4 v = acc[mi][ni];
      if (MODE == 1) {
        float cpv[4];
        const float gv[4] = { gv0, gv1, gv2, gv3 };
        #pragma unroll
        for (int j = 0; j < 4; ++j) {
          float t = v[j] + orig[(size_t)(row0 + j) * N + col];
          cpv[j] = tanhf(t * gv[j]);
          C[(size_t)(row0 + j) * N + col] = cpv[j];
        }
        u16x4 o = { f2bf(cpv[0]), f2bf(cpv[1]), f2bf(cpv[2]), f2bf(cpv[3]) };
        *(u16x4*)(CbT + (size_t)col * 2048 + row0) = o;
      } else {
        #pragma unroll
        for (int j = 0; j < 4; ++j)
          C[(size_t)(row0 + j) * N + col] = v[j];
      }
    }
  }
}

extern "C" void kernel_launch(void* const* d_in, const int* in_sizes, int n_in,
                              void* d_out, int out_size, void* d_ws, size_t ws_size,
                              hipStream_t stream) {
  const float* cp     = (const float*)d_in[0];
  const float* w1     = (const float*)d_in[1];
  const float* w2     = (const float*)d_in[2];
  const float* audio  = (const float*)d_in[3];
  const float* decays = (const float*)d_in[4];
  const float* gains  = (const float*)d_in[5];

  float* out0 = (float*)d_out;                   // audio_out: [t][w] flat
  float* out1 = out0 + (size_t)2048 * 4096;      // cp_out: [c][t]

  char* ws = (char*)d_ws;
  u16*   w1b    = (u16*)(ws);                    //  8 MB
  u16*   w2b    = (u16*)(ws + 8388608);          //  8 MB
  u16*   audiob = (u16*)(ws + 16777216);         //  8 MB
  float* orig   = (float*)(ws + 25165824);       // 32 MB
  u16*   yT     = (u16*)(ws + 58720256);         // 16 MB
  u16*   x0t    = (u16*)(ws + 75497472);         // 16 MB
  u16*   cpbT   = x0t;                           // reuse after GEMM1
  float* Lbuf   = (float*)(ws + 75497472);       // overlap (dead between GEMM1/GEMM2)
  float* Cin    = (float*)(ws + 75497472 + 524288);

  cvt_bf16_kernel<<<4096, 256, 0, stream>>>(w1, w1b, 1048576);
  cvt_bf16_kernel<<<4096, 256, 0, stream>>>(w2, w2b, 1048576);
  cvt_bf16_kernel<<<4096, 256, 0, stream>>>(audio, audiob, 1048576);
  relu_t_kernel<<<2048, 256, 0, stream>>>(cp, x0t);

  // x = w1 @ relu(cp) -> orig[2048][4096]   (grid 8bm x 32bn, xlog=2)
  gemm8_kernel<0><<<256, 512, 0, stream>>>(w1b, x0t, orig, 4096, 2048, 2,
                                           nullptr, nullptr, nullptr);
  // y = IIR(orig) -> yT[4096][2048] bf16
  iir_partial_kernel<<<1024, 128, 0, stream>>>(orig, decays, Lbuf);
  iir_carry_kernel<<<16, 128, 0, stream>>>(Lbuf, decays, Cin);
  iir_apply_kernel<<<1024, 128, 0, stream>>>(orig, decays, Cin, yT);
  // x2 = w2 @ y + orig; cp_out = tanh(x2*g) -> out1 f32, cpbT[t][c] bf16
  gemm8_kernel<1><<<256, 512, 0, stream>>>(w2b, yT, out1, 4096, 2048, 2,
                                           orig, gains, cpbT);
  // audio_out[t][w] = cpbT @ audiob^T   (grid 16bm x 16bn, xlog=1)
  gemm8_kernel<0><<<256, 512, 0, stream>>>(cpbT, audiob, out0, 2048, 2048, 1,
                                           nullptr, nullptr, nullptr);
}

// Round 5
// 187.545 us; speedup vs baseline: 1.3517x; 1.3517x over previous
//
#include <hip/hip_runtime.h>
#include <math.h>

typedef __attribute__((ext_vector_type(8))) short bf16x8;
typedef __attribute__((ext_vector_type(8))) unsigned short u16x8;
typedef __attribute__((ext_vector_type(4))) unsigned short u16x4;
typedef __attribute__((ext_vector_type(4))) float f32x4;
typedef unsigned short u16;

__device__ __forceinline__ u16 f2bf(float f) {
  unsigned u = __builtin_bit_cast(unsigned, f);
  return (u16)((u + 0x7FFFu + ((u >> 16) & 1u)) >> 16);
}

__device__ __forceinline__ void gload16(const u16* g, u16* l) {
  __builtin_amdgcn_global_load_lds((const __attribute__((address_space(1))) void*)g,
                                   (__attribute__((address_space(3))) void*)l, 16, 0, 0);
}

__device__ __forceinline__ void sbar() {
  __builtin_amdgcn_sched_barrier(0);
  __builtin_amdgcn_s_barrier();
  __builtin_amdgcn_sched_barrier(0);
}

#define VMWAIT(n) asm volatile("s_waitcnt vmcnt(" #n ")" ::: "memory")
#define MFMA16(a, b, c) __builtin_amdgcn_mfma_f32_16x16x32_bf16((a), (b), (c), 0, 0, 0)

__device__ __forceinline__ float decay_of(float d) {
  return 1e-12f + 0.5f + 0.5f / (1.0f + expf(-d));
}

// ---------------- prep: f32 -> bf16 ----------------
__global__ __launch_bounds__(256) void cvt_bf16_kernel(const float* __restrict__ in,
                                                       u16* __restrict__ out, int n4) {
  int i = blockIdx.x * 256 + threadIdx.x;
  if (i >= n4) return;
  const float4 v = ((const float4*)in)[i];
  u16x4 o = { f2bf(v.x), f2bf(v.y), f2bf(v.z), f2bf(v.w) };
  ((u16x4*)out)[i] = o;
}

// ---------------- prep: relu(cp) transposed to [t][c] bf16 ----------------
__global__ __launch_bounds__(256) void relu_t_kernel(const float* __restrict__ cp,
                                                     u16* __restrict__ x0t) {
  const int cb = blockIdx.x & 31;
  const int tb = blockIdx.x >> 5;
  __shared__ __attribute__((aligned(16))) float tile[64][65];
  const int tid = threadIdx.x;
  const int r0 = tid >> 4, i4 = (tid & 15) * 4;
  #pragma unroll
  for (int rr = 0; rr < 64; rr += 16) {
    const float4 v = *(const float4*)(cp + (size_t)(cb * 64 + r0 + rr) * 4096 + tb * 64 + i4);
    tile[r0 + rr][i4 + 0] = fmaxf(v.x, 0.f);
    tile[r0 + rr][i4 + 1] = fmaxf(v.y, 0.f);
    tile[r0 + rr][i4 + 2] = fmaxf(v.z, 0.f);
    tile[r0 + rr][i4 + 3] = fmaxf(v.w, 0.f);
  }
  __syncthreads();
  #pragma unroll
  for (int it = 0; it < 2; ++it) {
    const int chunk = it * 256 + tid;
    const int i = chunk >> 3, rp = (chunk & 7) * 8;
    u16x8 o;
    #pragma unroll
    for (int q = 0; q < 8; ++q) o[q] = f2bf(tile[rp + q][i]);
    *(u16x8*)(x0t + (size_t)(tb * 64 + i) * 2048 + cb * 64 + rp) = o;
  }
}

// ---------------- IIR blocked scan ----------------
__global__ __launch_bounds__(128) void iir_partial_kernel(const float* __restrict__ x,
                                                          const float* __restrict__ decays,
                                                          float* __restrict__ L) {
  const int tid = threadIdx.x;
  const int cb = blockIdx.x & 15;
  const int ck = blockIdx.x >> 4;
  const int c0 = cb * 128, t0 = ck * 64;
  __shared__ __attribute__((aligned(16))) float xs[128][65];
  const float dd = decay_of(decays[c0 + tid]);
  #pragma unroll
  for (int it = 0; it < 16; ++it) {
    const int idx = it * 128 + tid;
    const int r = idx >> 4, iv = (idx & 15) * 4;
    const float4 v = *(const float4*)(x + (size_t)(c0 + r) * 4096 + t0 + iv);
    xs[r][iv + 0] = v.x; xs[r][iv + 1] = v.y; xs[r][iv + 2] = v.z; xs[r][iv + 3] = v.w;
  }
  __syncthreads();
  float yv = 0.0f;
  #pragma unroll
  for (int i = 0; i < 64; ++i) yv = dd * (xs[tid][i] + yv);
  L[ck * 2048 + c0 + tid] = yv;
}

__global__ __launch_bounds__(128) void iir_carry_kernel(const float* __restrict__ L,
                                                        const float* __restrict__ decays,
                                                        float* __restrict__ Cin) {
  const int c = blockIdx.x * 128 + threadIdx.x;
  const float dd = decay_of(decays[c]);
  float A = dd;
  #pragma unroll
  for (int p = 0; p < 6; ++p) A = A * A;   // dd^64
  float carry = 0.0f;
  for (int j = 0; j < 64; ++j) {
    Cin[j * 2048 + c] = carry;
    carry = L[j * 2048 + c] + A * carry;
  }
}

__global__ __launch_bounds__(128) void iir_apply_kernel(const float* __restrict__ x,
                                                        const float* __restrict__ decays,
                                                        const float* __restrict__ Cin,
                                                        u16* __restrict__ yT) {
  const int tid = threadIdx.x;
  const int cb = blockIdx.x & 15;
  const int ck = blockIdx.x >> 4;
  const int c0 = cb * 128, t0 = ck * 64;
  __shared__ __attribute__((aligned(16))) float xs[128][65];
  __shared__ __attribute__((aligned(16))) u16 ys[64][136];
  const float dd = decay_of(decays[c0 + tid]);
  const float carry = Cin[ck * 2048 + c0 + tid];
  #pragma unroll
  for (int it = 0; it < 16; ++it) {
    const int idx = it * 128 + tid;
    const int r = idx >> 4, iv = (idx & 15) * 4;
    const float4 v = *(const float4*)(x + (size_t)(c0 + r) * 4096 + t0 + iv);
    xs[r][iv + 0] = v.x; xs[r][iv + 1] = v.y; xs[r][iv + 2] = v.z; xs[r][iv + 3] = v.w;
  }
  __syncthreads();
  float yv = carry;
  #pragma unroll
  for (int i = 0; i < 64; ++i) {
    yv = dd * (xs[tid][i] + yv);
    ys[i][tid] = f2bf(yv);
  }
  __syncthreads();
  #pragma unroll
  for (int it = 0; it < 8; ++it) {
    const int chunk = it * 128 + tid;
    const int i = chunk >> 4, cpv = (chunk & 15) * 8;
    u16x8 v = *(const u16x8*)&ys[i][cpv];
    *(u16x8*)(yT + (size_t)(t0 + i) * 2048 + c0 + cpv) = v;
  }
}

// ---------------- GEMM: 128x128 tile, BK=64, double-buffer, 2 blocks/CU ----------------
// C[M][N] = A[M][K] @ Bt[N][K]^T. 256 thr = 4 waves (2M x 2N), per-wave 64x64.
// Counted vmcnt(8) prefetch gate (no drain); XOR-swizzled LDS (0 conflicts);
// XCD-rect block swizzle; cross-block overlap from 2 resident blocks/CU.
template <int MODE>
__global__ __launch_bounds__(256, 2) void gemm_db_kernel(
    const u16* __restrict__ A, const u16* __restrict__ Bt, float* __restrict__ C,
    int N, int K, int xlogn,
    const float* __restrict__ orig, const float* __restrict__ gains,
    u16* __restrict__ CbT) {
  __shared__ __attribute__((aligned(16))) u16 Asb[2][128 * 64];  // 32 KB
  __shared__ __attribute__((aligned(16))) u16 Bsb[2][128 * 64];  // 32 KB
  const int tid = threadIdx.x;
  const int l = tid & 63, w = tid >> 6;
  // XCD-rect swizzle over 512 blocks: 8 XCDs in (xm x xn) grid, 8x8 rect each.
  const int xc = blockIdx.x & 7, rblk = blockIdx.x >> 3;
  const int xn = xc & ((1 << xlogn) - 1), xm = xc >> xlogn;
  const int bm = xm * 8 + (rblk >> 3);
  const int bn = xn * 8 + (rblk & 7);
  const int nt = K >> 6;

  // staging: wave w, unit u covers rows (u*4+w)*8 .. +7 of the 128-row tile.
  // lane l: row +(l>>3), fetch global 16B-chunk ((l&7) ^ (l>>3)) of the 128B row
  // -> LDS[r][c] = G[r][c ^ (r&7)] (involution; reads apply same XOR).
  const int cs = (l & 7) ^ (l >> 3);
  const int rsub = l >> 3;
  const u16* aS[4]; const u16* bS[4]; int tO[4];
  #pragma unroll
  for (int u = 0; u < 4; ++u) {
    const int rg = (u * 4 + w) * 8 + rsub;
    aS[u] = A  + (size_t)(bm * 128 + rg) * K + cs * 8;
    bS[u] = Bt + (size_t)(bn * 128 + rg) * K + cs * 8;
    tO[u] = (u * 4 + w) * 512;
  }

#define STAGE(bufA, bufB, tt) do {                                        \
    const long so_ = (long)(tt) * 64;                                     \
    gload16(aS[0] + so_, (bufA) + tO[0]); gload16(aS[1] + so_, (bufA) + tO[1]); \
    gload16(aS[2] + so_, (bufA) + tO[2]); gload16(aS[3] + so_, (bufA) + tO[3]); \
    gload16(bS[0] + so_, (bufB) + tO[0]); gload16(bS[1] + so_, (bufB) + tO[1]); \
    gload16(bS[2] + so_, (bufB) + tO[2]); gload16(bS[3] + so_, (bufB) + tO[3]); \
  } while (0)

  // prologue: tiles 0 and 1
  STAGE((u16*)Asb[0], (u16*)Bsb[0], 0);
  STAGE((u16*)Asb[1], (u16*)Bsb[1], 1);

  f32x4 acc[4][4];
  #pragma unroll
  for (int i = 0; i < 4; ++i)
    #pragma unroll
    for (int j = 0; j < 4; ++j) acc[i][j] = (f32x4){0.f, 0.f, 0.f, 0.f};

  const int wr = w >> 1, wc = w & 1;
  const int rA0 = wr * 64 + (l & 15);
  const int rB0 = wc * 64 + (l & 15);
  const int jk0 = (l >> 4) ^ (l & 7);        // swizzled chunk, k-half 0
  const int jk1 = ((l >> 4) + 4) ^ (l & 7);  // swizzled chunk, k-half 1

  VMWAIT(8);   // tile 0 landed (tile 1 in flight)
  sbar();

  for (int t = 0; t < nt; ++t) {
    const u16* Ac = Asb[t & 1];
    const u16* Bc = Bsb[t & 1];
    bf16x8 a0[4], b0[4], a1[4], b1[4];
    #pragma unroll
    for (int mi = 0; mi < 4; ++mi)
      a0[mi] = *(const bf16x8*)(Ac + (rA0 + mi * 16) * 64 + jk0 * 8);
    #pragma unroll
    for (int ni = 0; ni < 4; ++ni)
      b0[ni] = *(const bf16x8*)(Bc + (rB0 + ni * 16) * 64 + jk0 * 8);
    #pragma unroll
    for (int mi = 0; mi < 4; ++mi)
      a1[mi] = *(const bf16x8*)(Ac + (rA0 + mi * 16) * 64 + jk1 * 8);
    #pragma unroll
    for (int ni = 0; ni < 4; ++ni)
      b1[ni] = *(const bf16x8*)(Bc + (rB0 + ni * 16) * 64 + jk1 * 8);
    __builtin_amdgcn_s_setprio(1);
    #pragma unroll
    for (int mi = 0; mi < 4; ++mi)
      #pragma unroll
      for (int ni = 0; ni < 4; ++ni)
        acc[mi][ni] = MFMA16(a0[mi], b0[ni], acc[mi][ni]);
    #pragma unroll
    for (int mi = 0; mi < 4; ++mi)
      #pragma unroll
      for (int ni = 0; ni < 4; ++ni)
        acc[mi][ni] = MFMA16(a1[mi], b1[ni], acc[mi][ni]);
    __builtin_amdgcn_s_setprio(0);
    sbar();   // all waves done reading buf[t&1] (lgkm drained by MFMA deps)
    if (t + 2 < nt) {
      STAGE((u16*)Asb[t & 1], (u16*)Bsb[t & 1], t + 2);
      VMWAIT(8);            // tile t+1 landed; t+2's 8 loads stay in flight
    } else if (t + 1 < nt) {
      VMWAIT(0);            // last prefetched tile
    }
    sbar();
  }
#undef STAGE

  // ---------------- epilogue ----------------
  const int rb = bm * 128 + wr * 64 + ((l >> 4) * 4);
  const int cb = bn * 128 + wc * 64 + (l & 15);
  #pragma unroll
  for (int mi = 0; mi < 4; ++mi) {
    const int row0 = rb + mi * 16;
    float gv[4] = {0.f, 0.f, 0.f, 0.f};
    if (MODE == 1) {
      #pragma unroll
      for (int j = 0; j < 4; ++j) gv[j] = 5.0f / (1.0f + expf(-gains[row0 + j]));
    }
    #pragma unroll
    for (int ni = 0; ni < 4; ++ni) {
      const int col = cb + ni * 16;
      f32x4 v = acc[mi][ni];
      if (MODE == 1) {
        float cpv[4];
        #pragma unroll
        for (int j = 0; j < 4; ++j) {
          float t = v[j] + orig[(size_t)(row0 + j) * N + col];
          cpv[j] = tanhf(t * gv[j]);
          C[(size_t)(row0 + j) * N + col] = cpv[j];
        }
        u16x4 o = { f2bf(cpv[0]), f2bf(cpv[1]), f2bf(cpv[2]), f2bf(cpv[3]) };
        *(u16x4*)(CbT + (size_t)col * 2048 + row0) = o;
      } else {
        #pragma unroll
        for (int j = 0; j < 4; ++j)
          C[(size_t)(row0 + j) * N + col] = v[j];
      }
    }
  }
}

extern "C" void kernel_launch(void* const* d_in, const int* in_sizes, int n_in,
                              void* d_out, int out_size, void* d_ws, size_t ws_size,
                              hipStream_t stream) {
  const float* cp     = (const float*)d_in[0];
  const float* w1     = (const float*)d_in[1];
  const float* w2     = (const float*)d_in[2];
  const float* audio  = (const float*)d_in[3];
  const float* decays = (const float*)d_in[4];
  const float* gains  = (const float*)d_in[5];

  float* out0 = (float*)d_out;                   // audio_out: [t][w] flat
  float* out1 = out0 + (size_t)2048 * 4096;      // cp_out: [c][t]

  char* ws = (char*)d_ws;
  u16*   w1b    = (u16*)(ws);                    //  8 MB
  u16*   w2b    = (u16*)(ws + 8388608);          //  8 MB
  u16*   audiob = (u16*)(ws + 16777216);         //  8 MB
  float* orig   = (float*)(ws + 25165824);       // 32 MB
  u16*   yT     = (u16*)(ws + 58720256);         // 16 MB
  u16*   x0t    = (u16*)(ws + 75497472);         // 16 MB
  u16*   cpbT   = x0t;                           // reuse after GEMM1
  float* Lbuf   = (float*)(ws + 75497472);       // overlap (dead between GEMM1/GEMM2)
  float* Cin    = (float*)(ws + 75497472 + 524288);

  cvt_bf16_kernel<<<4096, 256, 0, stream>>>(w1, w1b, 1048576);
  cvt_bf16_kernel<<<4096, 256, 0, stream>>>(w2, w2b, 1048576);
  cvt_bf16_kernel<<<4096, 256, 0, stream>>>(audio, audiob, 1048576);
  relu_t_kernel<<<2048, 256, 0, stream>>>(cp, x0t);

  // x = w1 @ relu(cp) -> orig[2048][4096]   (16bm x 32bn; XCD grid 2x4)
  gemm_db_kernel<0><<<512, 256, 0, stream>>>(w1b, x0t, orig, 4096, 2048, 2,
                                             nullptr, nullptr, nullptr);
  // y = IIR(orig) -> yT[4096][2048] bf16
  iir_partial_kernel<<<1024, 128, 0, stream>>>(orig, decays, Lbuf);
  iir_carry_kernel<<<16, 128, 0, stream>>>(Lbuf, decays, Cin);
  iir_apply_kernel<<<1024, 128, 0, stream>>>(orig, decays, Cin, yT);
  // x2 = w2 @ y + orig; cp_out = tanh(x2*g) -> out1 f32, cpbT[t][c] bf16
  gemm_db_kernel<1><<<512, 256, 0, stream>>>(w2b, yT, out1, 4096, 2048, 2,
                                             orig, gains, cpbT);
  // audio_out[t][w] = cpbT @ audiob^T   (32bm x 16bn; XCD grid 4x2)
  gemm_db_kernel<0><<<512, 256, 0, stream>>>(cpbT, audiob, out0, 2048, 2048, 1,
                                             nullptr, nullptr, nullptr);
}